// Round 1
// baseline (577.720 us; speedup 1.0000x reference)
//
#include <hip/hip_runtime.h>

#define BB 8
#define HH 256
#define WW 256
#define CC 128
#define HW (HH*WW)
#define NP (BB*HW)          // 524288 pixels
#define THRESHOLD 0.8f
#define EPSV 1e-3f

// ---------------- K1: channel max/mean pool. One wave (64 lanes) per pixel.
__global__ __launch_bounds__(256) void k_pool(const float* __restrict__ in,
                                              float2* __restrict__ pooled) {
    int p    = blockIdx.x * 4 + (threadIdx.x >> 6);   // pixel index
    int lane = threadIdx.x & 63;
    const float2 v = *reinterpret_cast<const float2*>(in + (size_t)p * CC + lane * 2);
    float mx = fmaxf(v.x, v.y);
    float sm = v.x + v.y;
#pragma unroll
    for (int m = 32; m >= 1; m >>= 1) {
        mx = fmaxf(mx, __shfl_xor(mx, m));
        sm += __shfl_xor(sm, m);
    }
    if (lane == 0) pooled[p] = make_float2(mx, sm * (1.0f / 128.0f));
}

// ---------------- K2a: 3x3 conv (2ch -> 1) + sigmoid -> x, mask
__global__ __launch_bounds__(256) void k_conv_sr(const float2* __restrict__ pooled,
                                                 const float* __restrict__ w_sr,
                                                 const float* __restrict__ b_sr,
                                                 float* __restrict__ x,
                                                 float* __restrict__ mask) {
    int p = blockIdx.x * 256 + threadIdx.x;
    int b = p >> 16;
    int hw = p & 65535;
    int h = hw >> 8, w = hw & 255;
    float acc = b_sr[0];
#pragma unroll
    for (int kh = 0; kh < 3; ++kh) {
        int hh = h + kh - 1;
        if ((unsigned)hh >= HH) continue;
#pragma unroll
        for (int kw = 0; kw < 3; ++kw) {
            int ww = w + kw - 1;
            if ((unsigned)ww >= WW) continue;
            float2 pv = pooled[(size_t)b * HW + hh * WW + ww];
            acc += pv.x * w_sr[(kh * 3 + kw) * 2 + 0] + pv.y * w_sr[(kh * 3 + kw) * 2 + 1];
        }
    }
    float s = 1.0f / (1.0f + expf(-acc));
    x[p] = s;
    mask[p] = (s > THRESHOLD) ? 1.0f : 0.0f;
}

// ---------------- K2b: 3x3 convs (1ch -> 1) over x -> gamma, beta
__global__ __launch_bounds__(256) void k_conv_gb(const float* __restrict__ x,
                                                 const float* __restrict__ w_gamma,
                                                 const float* __restrict__ b_gamma,
                                                 const float* __restrict__ w_beta,
                                                 const float* __restrict__ b_beta,
                                                 float* __restrict__ gamma,
                                                 float* __restrict__ beta) {
    int p = blockIdx.x * 256 + threadIdx.x;
    int b = p >> 16;
    int hw = p & 65535;
    int h = hw >> 8, w = hw & 255;
    float ag = b_gamma[0], ab = b_beta[0];
#pragma unroll
    for (int kh = 0; kh < 3; ++kh) {
        int hh = h + kh - 1;
        if ((unsigned)hh >= HH) continue;
#pragma unroll
        for (int kw = 0; kw < 3; ++kw) {
            int ww = w + kw - 1;
            if ((unsigned)ww >= WW) continue;
            float xv = x[(size_t)b * HW + hh * WW + ww];
            ag += xv * w_gamma[kh * 3 + kw];
            ab += xv * w_beta[kh * 3 + kw];
        }
    }
    gamma[p] = ag;
    beta[p] = ab;
}

// ---------------- K3: per-(B,C) masked moments. 256 chunks per batch, 256 px/chunk.
// acc layout: [0]=sum_v, [1024]=sumsq_v, [2048]=sum_m, [3072]=sumsq_m (each B*C=1024)
__global__ __launch_bounds__(256) void k_moments(const float* __restrict__ in,
                                                 const float* __restrict__ mask,
                                                 float* __restrict__ acc,
                                                 float* __restrict__ cnt) {
    int b     = blockIdx.x >> 8;
    int chunk = blockIdx.x & 255;
    int tid   = threadIdx.x;
    int c     = tid & 127;
    int half  = tid >> 7;
    float s_v = 0.f, ss_v = 0.f, s_m = 0.f, ss_m = 0.f, cv = 0.f;
    int base = chunk * 256;
    for (int i = 0; i < 128; ++i) {
        int pl = base + i * 2 + half;
        size_t p = (size_t)b * HW + pl;
        float m = mask[p];                       // wave-uniform
        float v = in[p * CC + c];
        float v2 = v * v;
        if (m > 0.5f) { s_v += v; ss_v += v2; }
        else          { s_m += v; ss_m += v2; }
        cv += m;
    }
    __shared__ float sh[5][256];
    sh[0][tid] = s_v; sh[1][tid] = ss_v; sh[2][tid] = s_m; sh[3][tid] = ss_m; sh[4][tid] = cv;
    __syncthreads();
    if (tid < 128) {
        atomicAdd(&acc[0 * 1024 + b * 128 + tid], sh[0][tid] + sh[0][tid + 128]);
        atomicAdd(&acc[1 * 1024 + b * 128 + tid], sh[1][tid] + sh[1][tid + 128]);
        atomicAdd(&acc[2 * 1024 + b * 128 + tid], sh[2][tid] + sh[2][tid + 128]);
        atomicAdd(&acc[3 * 1024 + b * 128 + tid], sh[3][tid] + sh[3][tid + 128]);
    }
    if (tid == 0) atomicAdd(&cnt[b], sh[4][0] + sh[4][128]);
}

// ---------------- K3.5: sums -> mu, 1/sqrt(sig+eps), per region
// stats layout: [0]=mu_v, [1024]=rs_v, [2048]=mu_m, [3072]=rs_m
__global__ void k_stats(const float* __restrict__ acc, const float* __restrict__ cnt,
                        float* __restrict__ stats) {
    int i = blockIdx.x * 256 + threadIdx.x;
    if (i >= 1024) return;
    int b = i >> 7;
    float cv = cnt[b];
    float cm = (float)HW - cv;
    float s_v = acc[i], ss_v = acc[1024 + i], s_m = acc[2048 + i], ss_m = acc[3072 + i];
    float fs_v = cv + EPSV;
    float mu_v = s_v / fs_v;
    float sig_v = (ss_v - 2.f * mu_v * s_v + mu_v * mu_v * cv) / fs_v;
    float fs_m = cm + EPSV;
    float mu_m = s_m / fs_m;
    float sig_m = (ss_m - 2.f * mu_m * s_m + mu_m * mu_m * cm) / fs_m;
    stats[i]        = mu_v;
    stats[1024 + i] = 1.0f / sqrtf(sig_v + EPSV);
    stats[2048 + i] = mu_m;
    stats[3072 + i] = 1.0f / sqrtf(sig_m + EPSV);
}

// ---------------- K4: apply. One float4 per thread.
__global__ __launch_bounds__(256) void k_apply(const float* __restrict__ in,
                                               const float* __restrict__ mask,
                                               const float* __restrict__ beta,
                                               const float* __restrict__ gamma,
                                               const float* __restrict__ stats,
                                               float* __restrict__ out) {
    size_t idx = (size_t)blockIdx.x * 256 + threadIdx.x;  // float4 index
    size_t p = idx >> 5;                                  // 32 float4 per pixel
    int c4 = (int)(idx & 31);
    int b = (int)(p >> 16);
    const float4 v = reinterpret_cast<const float4*>(in)[idx];
    float m  = mask[p];
    float be = beta[p];
    float ga = gamma[p];
    int si = b * 128 + c4 * 4;
    float4 mu, rs;
    if (m > 0.5f) {
        mu = *reinterpret_cast<const float4*>(stats + si);
        rs = *reinterpret_cast<const float4*>(stats + 1024 + si);
    } else {
        mu = *reinterpret_cast<const float4*>(stats + 2048 + si);
        rs = *reinterpret_cast<const float4*>(stats + 3072 + si);
    }
    float4 o;
    o.x = (v.x - mu.x) * rs.x * be + ga;
    o.y = (v.y - mu.y) * rs.y * be + ga;
    o.z = (v.z - mu.z) * rs.z * be + ga;
    o.w = (v.w - mu.w) * rs.w * be + ga;
    reinterpret_cast<float4*>(out)[idx] = o;
}

extern "C" void kernel_launch(void* const* d_in, const int* in_sizes, int n_in,
                              void* d_out, int out_size, void* d_ws, size_t ws_size,
                              hipStream_t stream) {
    const float* in      = (const float*)d_in[0];
    const float* w_sr    = (const float*)d_in[1];
    const float* b_sr    = (const float*)d_in[2];
    const float* w_gamma = (const float*)d_in[3];
    const float* b_gamma = (const float*)d_in[4];
    const float* w_beta  = (const float*)d_in[5];
    const float* b_beta  = (const float*)d_in[6];
    float* out = (float*)d_out;
    float* ws  = (float*)d_ws;

    float2* pooled = (float2*)ws;                 // 2*NP floats
    float* x     = ws + 2 * (size_t)NP;           // NP
    float* mask  = ws + 3 * (size_t)NP;           // NP
    float* beta  = ws + 4 * (size_t)NP;           // NP
    float* gamma = ws + 5 * (size_t)NP;           // NP
    float* acc   = ws + 6 * (size_t)NP;           // 4096
    float* cnt   = acc + 4096;                    // 8
    float* stats = cnt + 8;                       // 4096 (16B-aligned offset)

    hipMemsetAsync(acc, 0, (4096 + 8) * sizeof(float), stream);

    k_pool   <<<NP / 4,  256, 0, stream>>>(in, pooled);
    k_conv_sr<<<NP / 256, 256, 0, stream>>>(pooled, w_sr, b_sr, x, mask);
    k_conv_gb<<<NP / 256, 256, 0, stream>>>(x, w_gamma, b_gamma, w_beta, b_beta, gamma, beta);
    k_moments<<<BB * 256, 256, 0, stream>>>(in, mask, acc, cnt);
    k_stats  <<<4, 256, 0, stream>>>(acc, cnt, stats);
    k_apply  <<<(NP * (size_t)CC / 4) / 256, 256, 0, stream>>>(in, mask, beta, gamma, stats, out);
}